// Round 2
// baseline (1096.871 us; speedup 1.0000x reference)
//
#include <hip/hip_runtime.h>
#include <math.h>

typedef unsigned short u16;
typedef __attribute__((ext_vector_type(8))) short short8;
typedef __attribute__((ext_vector_type(4))) float floatx4;

__device__ __forceinline__ u16 f2bf(float f) {
    union { float f; unsigned u; } v; v.f = f;
    unsigned r = v.u + 0x7fffu + ((v.u >> 16) & 1u);
    return (u16)(r >> 16);
}

struct WPtrs {
    const float* w1[5];
    const float* b1[5];
    const float* w2[5];
};

// ---------------- prep: transpose + pad weights to bf16, precompute tpe ----------------
// W1t: [head][n][k] 5*256*256 bf16 (W1t[h][n][k] = W1_h[k][n], zero-padded)
// W2t: rows (mask@0 x16, pos@16 x16, scl@32 x16, rot@48 x16, shs@64 x48) * 256k
// b1p: [head][n] 5*256 fp32, col 255 zero
// enc: 64 bf16, relu'd time positional encoding (row-invariant)
__global__ void prep_weights(WPtrs p, const float* __restrict__ te,
                             u16* __restrict__ W1t, u16* __restrict__ W2t,
                             float* __restrict__ b1p, u16* __restrict__ enc)
{
    int gid = blockIdx.x * 256 + threadIdx.x;
    if (gid < 5 * 256 * 256) {
        int h   = gid >> 16;
        int rem = gid & 65535;
        int nn  = rem >> 8;
        int k   = rem & 255;
        float v = (nn < 255 && k < 255) ? p.w1[h][k * 255 + nn] : 0.0f;
        W1t[gid] = f2bf(v);
    }
    if (gid < 112 * 256) {
        int row = gid >> 8;
        int k   = gid & 255;
        int h, roff, od;
        if (row < 16)      { h = 0; roff = 0;  od = 1; }
        else if (row < 32) { h = 1; roff = 16; od = 3; }
        else if (row < 48) { h = 2; roff = 32; od = 3; }
        else if (row < 64) { h = 3; roff = 48; od = 4; }
        else               { h = 4; roff = 64; od = 48; }
        int nn = row - roff;
        float v = (k < 255 && nn < od) ? p.w2[h][k * od + nn] : 0.0f;
        W2t[gid] = f2bf(v);
    }
    if (gid < 5 * 256) {
        int h  = gid >> 8;
        int nn = gid & 255;
        b1p[gid] = (nn < 255) ? p.b1[h][nn] : 0.0f;
    }
    if (gid < 64) {
        float t = te[0];
        float fi = (float)(gid & ~1);                    // 2*(gid>>1)
        float freq = powf(10000.0f, fi * (1.0f / 32.0f));
        float a = t / freq;
        float v = (gid & 1) ? cosf(a) : sinf(a);
        enc[gid] = f2bf(fmaxf(v, 0.0f));
    }
}

// ---------------- build x = relu(concat(features)) bf16, cols padded to 256 ----------------
__global__ void build_x(const float* __restrict__ opa, const float* __restrict__ shs,
                        const float* __restrict__ te,  const float* __restrict__ sem,
                        const float* __restrict__ pt,  const float* __restrict__ scl,
                        const float* __restrict__ rot, const float* __restrict__ dx,
                        const u16* __restrict__ enc,
                        u16* __restrict__ x, int n)
{
    int row = blockIdx.x;
    if (row >= n) return;
    int c = threadIdx.x;
    u16 o;
    if (c >= 191 && c < 255) {
        o = enc[c - 191];                    // precomputed, already relu+bf16
    } else {
        float v;
        if (c < 3)        v = pt[row * 3 + c];
        else if (c < 7)   v = rot[row * 4 + (c - 3)];
        else if (c < 10)  v = scl[row * 3 + (c - 7)];
        else if (c < 11)  v = opa[row];
        else if (c < 59)  v = shs[(size_t)row * 48 + (c - 11)];
        else if (c < 187) v = sem[(size_t)row * 128 + (c - 59)];
        else if (c < 190) v = dx[row * 3 + (c - 187)];
        else if (c < 191) v = te[row];
        else v = 0.0f;                       // c == 255 pad
        o = f2bf(fmaxf(v, 0.0f));
    }
    x[(size_t)row * 256 + c] = o;
}

// ---------------- fused 5-head MLP, barrier-free ----------------
// block = 256 threads = 4 waves; wave owns 32 rows (2 row-tiles of 16) x 256 cols.
// Phase1: A-frags + B-frags direct from global (L1/L2-resident weights), acc[2][16].
// h1 -> wave-private LDS (16 rows x 264, 2-way-conflict-free), per row-tile.
// Phase2: B2 from global (W2t 57KB, L1-hot). No __syncthreads anywhere.
template<int NCT>
__device__ __forceinline__ void head_compute(
    const u16* __restrict__ x, const u16* __restrict__ W1t_h,
    const u16* __restrict__ W2t_r, const float* __restrict__ b1_h,
    u16* __restrict__ Hw, int row0, int n, int q, int ln,
    floatx4 acc2[2][3])
{
    floatx4 acc[2][16];
#pragma unroll
    for (int t = 0; t < 2; ++t)
#pragma unroll
        for (int ct = 0; ct < 16; ++ct) acc[t][ct] = (floatx4){0.f, 0.f, 0.f, 0.f};

    const int r0 = min(row0 + ln,      n - 1);
    const int r1 = min(row0 + 16 + ln, n - 1);
    const u16* xa0 = x + (size_t)r0 * 256 + q * 8;
    const u16* xa1 = x + (size_t)r1 * 256 + q * 8;
    const u16* wb  = W1t_h + ln * 256 + q * 8;

#pragma unroll
    for (int kk = 0; kk < 8; ++kk) {
        short8 a0 = *(const short8*)(xa0 + kk * 32);
        short8 a1 = *(const short8*)(xa1 + kk * 32);
        short8 bf[8];
#pragma unroll
        for (int ct = 0; ct < 8; ++ct)
            bf[ct] = *(const short8*)(wb + (ct * 16) * 256 + kk * 32);
#pragma unroll
        for (int ct = 0; ct < 8; ++ct) {
            acc[0][ct] = __builtin_amdgcn_mfma_f32_16x16x32_bf16(a0, bf[ct], acc[0][ct], 0, 0, 0);
            acc[1][ct] = __builtin_amdgcn_mfma_f32_16x16x32_bf16(a1, bf[ct], acc[1][ct], 0, 0, 0);
        }
#pragma unroll
        for (int ct = 0; ct < 8; ++ct)
            bf[ct] = *(const short8*)(wb + ((ct + 8) * 16) * 256 + kk * 32);
#pragma unroll
        for (int ct = 0; ct < 8; ++ct) {
            acc[0][ct + 8] = __builtin_amdgcn_mfma_f32_16x16x32_bf16(a0, bf[ct], acc[0][ct + 8], 0, 0, 0);
            acc[1][ct + 8] = __builtin_amdgcn_mfma_f32_16x16x32_bf16(a1, bf[ct], acc[1][ct + 8], 0, 0, 0);
        }
    }

#pragma unroll
    for (int t = 0; t < 2; ++t) {
        // h1 = relu(acc + b1) -> wave-private LDS (reused across t; same-wave lgkm ordering)
#pragma unroll
        for (int ct = 0; ct < 16; ++ct) {
            float b1v = b1_h[ct * 16 + ln];
#pragma unroll
            for (int r = 0; r < 4; ++r)
                Hw[(q * 4 + r) * 264 + ct * 16 + ln] = f2bf(fmaxf(acc[t][ct][r] + b1v, 0.0f));
        }
#pragma unroll
        for (int c2 = 0; c2 < NCT; ++c2) acc2[t][c2] = (floatx4){0.f, 0.f, 0.f, 0.f};
#pragma unroll
        for (int ks = 0; ks < 8; ++ks) {
            short8 a2 = *(const short8*)&Hw[ln * 264 + ks * 32 + q * 8];
#pragma unroll
            for (int c2 = 0; c2 < NCT; ++c2) {
                short8 b2 = *(const short8*)(W2t_r + (c2 * 16 + ln) * 256 + ks * 32 + q * 8);
                acc2[t][c2] = __builtin_amdgcn_mfma_f32_16x16x32_bf16(a2, b2, acc2[t][c2], 0, 0, 0);
            }
        }
    }
}

__global__ __launch_bounds__(256, 2) void fused_heads(
    const u16* __restrict__ x, const u16* __restrict__ W1t,
    const u16* __restrict__ W2t, const float* __restrict__ b1p,
    const float* __restrict__ b2m, const float* __restrict__ b2p,
    const float* __restrict__ b2s, const float* __restrict__ b2r,
    const float* __restrict__ b2h,
    const float* __restrict__ pt, const float* __restrict__ scl,
    const float* __restrict__ rot, const float* __restrict__ shs,
    const float* __restrict__ opa, float* __restrict__ out, int n)
{
    __shared__ __attribute__((aligned(16))) u16 Hsm[4 * 16 * 264];
    __shared__ float Msm[4 * 32];

    const int tid  = threadIdx.x;
    const int wave = tid >> 6;
    const int lane = tid & 63;
    const int q    = lane >> 4;
    const int ln   = lane & 15;
    const int row0 = blockIdx.x * 128 + wave * 32;   // wave's first row
    u16*   Hw = Hsm + wave * (16 * 264);
    float* Mw = Msm + wave * 32;
    const size_t NN = (size_t)n;

    floatx4 acc2[2][3];

    // ---- head 0: mask (sigmoid) + opacity copy ----
    head_compute<1>(x, W1t, W2t, b1p, Hw, row0, n, q, ln, acc2);
    {
        float bb = b2m[0];
#pragma unroll
        for (int t = 0; t < 2; ++t) {
            if (ln == 0) {
#pragma unroll
                for (int r = 0; r < 4; ++r) {
                    float raw = acc2[t][0][r] + bb;
                    Mw[t * 16 + q * 4 + r] = 1.0f / (1.0f + expf(-raw));
                }
            }
            if (ln == 1) {
#pragma unroll
                for (int r = 0; r < 4; ++r) {
                    int grow = row0 + t * 16 + q * 4 + r;
                    if (grow < n) out[10 * NN + grow] = opa[grow];
                }
            }
        }
    }
    float mk[2][4];
#pragma unroll
    for (int t = 0; t < 2; ++t)
#pragma unroll
        for (int r = 0; r < 4; ++r) mk[t][r] = Mw[t * 16 + q * 4 + r];

    // ---- head 1: pos -> dx_out + pts ----
    head_compute<1>(x, W1t + 1 * 65536, W2t + 16 * 256, b1p + 1 * 256, Hw, row0, n, q, ln, acc2);
    if (ln < 3) {
        float bb = b2p[ln];
#pragma unroll
        for (int t = 0; t < 2; ++t)
#pragma unroll
            for (int r = 0; r < 4; ++r) {
                int grow = row0 + t * 16 + q * 4 + r;
                if (grow < n) {
                    float raw = acc2[t][0][r] + bb;
                    out[59 * NN + (size_t)grow * 3 + ln] = raw;
                    out[(size_t)grow * 3 + ln] = pt[(size_t)grow * 3 + ln] + raw * mk[t][r];
                }
            }
    }

    // ---- head 2: scl -> scales ----
    head_compute<1>(x, W1t + 2 * 65536, W2t + 32 * 256, b1p + 2 * 256, Hw, row0, n, q, ln, acc2);
    if (ln < 3) {
        float bb = b2s[ln];
#pragma unroll
        for (int t = 0; t < 2; ++t)
#pragma unroll
            for (int r = 0; r < 4; ++r) {
                int grow = row0 + t * 16 + q * 4 + r;
                if (grow < n) {
                    float raw = acc2[t][0][r] + bb;
                    out[3 * NN + (size_t)grow * 3 + ln] = scl[(size_t)grow * 3 + ln] + raw * mk[t][r];
                }
            }
    }

    // ---- head 3: rot -> rotations ----
    head_compute<1>(x, W1t + 3 * 65536, W2t + 48 * 256, b1p + 3 * 256, Hw, row0, n, q, ln, acc2);
    if (ln < 4) {
        float bb = b2r[ln];
#pragma unroll
        for (int t = 0; t < 2; ++t)
#pragma unroll
            for (int r = 0; r < 4; ++r) {
                int grow = row0 + t * 16 + q * 4 + r;
                if (grow < n) {
                    float raw = acc2[t][0][r] + bb;
                    out[6 * NN + (size_t)grow * 4 + ln] = rot[(size_t)grow * 4 + ln] + raw * mk[t][r];
                }
            }
    }

    // ---- head 4: shs -> dshs + shs ----
    head_compute<3>(x, W1t + 4 * 65536, W2t + 64 * 256, b1p + 4 * 256, Hw, row0, n, q, ln, acc2);
#pragma unroll
    for (int c2 = 0; c2 < 3; ++c2) {
        int n2 = c2 * 16 + ln;   // 0..47
        float bb = b2h[n2];
#pragma unroll
        for (int t = 0; t < 2; ++t)
#pragma unroll
            for (int r = 0; r < 4; ++r) {
                int grow = row0 + t * 16 + q * 4 + r;
                if (grow < n) {
                    float raw = acc2[t][c2][r] + bb;
                    out[62 * NN + (size_t)grow * 48 + n2] = raw;
                    out[11 * NN + (size_t)grow * 48 + n2] = shs[(size_t)grow * 48 + n2] + raw * mk[t][r];
                }
            }
    }
}

extern "C" void kernel_launch(void* const* d_in, const int* in_sizes, int n_in,
                              void* d_out, int out_size, void* d_ws, size_t ws_size,
                              hipStream_t stream)
{
    const float* opa  = (const float*)d_in[0];
    const float* shs  = (const float*)d_in[1];
    const float* te   = (const float*)d_in[2];
    const float* sem  = (const float*)d_in[3];
    const float* pt   = (const float*)d_in[4];
    const float* scl  = (const float*)d_in[5];
    const float* rot  = (const float*)d_in[6];
    const float* dx   = (const float*)d_in[7];

    WPtrs p;
    p.w1[0] = (const float*)d_in[8];  p.b1[0] = (const float*)d_in[9];  p.w2[0] = (const float*)d_in[10];
    p.w1[1] = (const float*)d_in[12]; p.b1[1] = (const float*)d_in[13]; p.w2[1] = (const float*)d_in[14];
    p.w1[2] = (const float*)d_in[16]; p.b1[2] = (const float*)d_in[17]; p.w2[2] = (const float*)d_in[18];
    p.w1[3] = (const float*)d_in[20]; p.b1[3] = (const float*)d_in[21]; p.w2[3] = (const float*)d_in[22];
    p.w1[4] = (const float*)d_in[24]; p.b1[4] = (const float*)d_in[25]; p.w2[4] = (const float*)d_in[26];
    const float* b2m = (const float*)d_in[11];
    const float* b2p = (const float*)d_in[15];
    const float* b2s = (const float*)d_in[19];
    const float* b2r = (const float*)d_in[23];
    const float* b2h = (const float*)d_in[27];

    const int n = in_sizes[0];               // 200000

    // workspace layout
    char* ws = (char*)d_ws;
    u16* x   = (u16*)ws;                                   // n*256 bf16
    u16* W1t = (u16*)(ws + (size_t)n * 256 * 2);           // 5*256*256 bf16
    u16* W2t = W1t + 5 * 256 * 256;                        // 112*256 bf16
    float* b1p = (float*)(W2t + 112 * 256);                // 5*256 fp32
    u16* enc = (u16*)(b1p + 5 * 256);                      // 64 bf16

    prep_weights<<<1280, 256, 0, stream>>>(p, te, W1t, W2t, b1p, enc);
    build_x<<<n, 256, 0, stream>>>(opa, shs, te, sem, pt, scl, rot, dx, enc, x, n);
    fused_heads<<<(n + 127) / 128, 256, 0, stream>>>(x, W1t, W2t, b1p,
                                                     b2m, b2p, b2s, b2r, b2h,
                                                     pt, scl, rot, shs, opa,
                                                     (float*)d_out, n);
}

// Round 3
// 833.830 us; speedup vs baseline: 1.3155x; 1.3155x over previous
//
#include <hip/hip_runtime.h>
#include <math.h>

typedef unsigned short u16;
typedef unsigned int u32;
typedef __attribute__((ext_vector_type(8))) short short8;
typedef __attribute__((ext_vector_type(4))) float floatx4;

__device__ __forceinline__ u16 f2bf(float f) {
    union { float f; unsigned u; } v; v.f = f;
    unsigned r = v.u + 0x7fffu + ((v.u >> 16) & 1u);
    return (u16)(r >> 16);
}

// ---------------- async global->LDS (16B per lane, wave-uniform LDS base) ----------------
typedef const __attribute__((address_space(1))) unsigned GUA;
typedef __attribute__((address_space(3))) unsigned LUA;

__device__ __forceinline__ void stage_w1(const void* gbase, void* lbase, int wave, int lane) {
    const char* g = (const char*)gbase;
    char* l = (char*)lbase;
#pragma unroll
    for (int i = 0; i < 16; ++i) {
        int off = (wave * 16 + i) * 1024;
        __builtin_amdgcn_global_load_lds((GUA*)(g + off + lane * 16), (LUA*)(l + off), 16, 0, 0);
    }
}

struct WPtrs {
    const float* w1[5];
    const float* w2[5];
};

// ---------------- prep ----------------
// W1t: [head][n][k-chunks swizzled]: element (h,n,k) at h*65536 + n*256 + ((kc ^ (n&31))<<3) + (k&7)
// W2t: [112][256] rows: mask@0(16), pos@16, scl@32, rot@48, shs@64(48); W2t[roff+n2][k]=w2[k*od+n2]
// enc: 64 bf16 relu'd time positional encoding
__global__ void prep_weights(WPtrs p, const float* __restrict__ te,
                             u16* __restrict__ W1t, u16* __restrict__ W2t,
                             u16* __restrict__ enc)
{
    const int bid = blockIdx.x;
    const int tid = threadIdx.x;
    if (bid < 80) {
        // W1 64x64 tile transpose + swizzle
        __shared__ float tile[64 * 65];
        int h = bid / 16, t = bid % 16;
        int k0 = (t / 4) * 64, n0 = (t % 4) * 64;
        int nn = tid & 63, g = tid >> 6;
        const float* w1 = p.w1[h];
#pragma unroll
        for (int rep = 0; rep < 16; ++rep) {
            int kl = g * 16 + rep;
            int k = k0 + kl, nidx = n0 + nn;
            float v = (k < 255 && nidx < 255) ? w1[k * 255 + nidx] : 0.0f;
            tile[kl * 65 + nn] = v;
        }
        __syncthreads();
#pragma unroll
        for (int i = 0; i < 2; ++i) {
            int c = tid * 2 + i;            // 0..511
            int nl = c >> 3, kcl = c & 7;
            int n = n0 + nl;
            int kcg = (k0 >> 3) + kcl;
            short8 sv;
#pragma unroll
            for (int j = 0; j < 8; ++j)
                sv[j] = (short)f2bf(tile[(kcl * 8 + j) * 65 + nl]);
            *(short8*)(W1t + h * 65536 + n * 256 + (((kcg ^ (n & 31))) << 3)) = sv;
        }
    } else if (bid < 192) {
        int row = bid - 80;               // 0..111
        int h, roff, od;
        if (row < 16)      { h = 0; roff = 0;  od = 1; }
        else if (row < 32) { h = 1; roff = 16; od = 3; }
        else if (row < 48) { h = 2; roff = 32; od = 3; }
        else if (row < 64) { h = 3; roff = 48; od = 4; }
        else               { h = 4; roff = 64; od = 48; }
        int n2 = row - roff;
        int k = tid;
        float v = (k < 255 && n2 < od) ? p.w2[h][k * od + n2] : 0.0f;
        W2t[row * 256 + k] = f2bf(v);
    } else {
        if (tid < 64) {
            float t = te[0];
            float fi = (float)(tid & ~1);
            float freq = powf(10000.0f, fi * (1.0f / 32.0f));
            float a = t / freq;
            float v = (tid & 1) ? cosf(a) : sinf(a);
            enc[tid] = f2bf(fmaxf(v, 0.0f));
        }
    }
}

// ---------------- build x = relu(concat) bf16, 256 cols; also copies opacity output ----------------
__global__ void build_x(const float* __restrict__ opa, const float* __restrict__ shs,
                        const float* __restrict__ te,  const float* __restrict__ sem,
                        const float* __restrict__ pt,  const float* __restrict__ scl,
                        const float* __restrict__ rot, const float* __restrict__ dx,
                        const u16* __restrict__ enc, float* __restrict__ out,
                        u16* __restrict__ x, int n)
{
    const int tid = threadIdx.x;
    const int row = blockIdx.x * 8 + (tid >> 5);
    const int c8  = tid & 31;
    if (row >= n) return;
    const size_t NN = (size_t)n;
    short8 sv;
    int c0 = c8 * 8;
    if (c0 >= 64 && c0 + 7 <= 183) {
        // pure semantic_feature fast path (cols 64..183 within [59,187))
        const float* s = sem + (size_t)row * 128 + (c0 - 59);
        float4 a = *(const float4*)(s);
        float4 b = *(const float4*)(s + 4);
        sv[0] = (short)f2bf(fmaxf(a.x, 0.f)); sv[1] = (short)f2bf(fmaxf(a.y, 0.f));
        sv[2] = (short)f2bf(fmaxf(a.z, 0.f)); sv[3] = (short)f2bf(fmaxf(a.w, 0.f));
        sv[4] = (short)f2bf(fmaxf(b.x, 0.f)); sv[5] = (short)f2bf(fmaxf(b.y, 0.f));
        sv[6] = (short)f2bf(fmaxf(b.z, 0.f)); sv[7] = (short)f2bf(fmaxf(b.w, 0.f));
    } else {
#pragma unroll
        for (int j = 0; j < 8; ++j) {
            int c = c0 + j;
            float v;
            if (c < 3)        v = pt[row * 3 + c];
            else if (c < 7)   v = rot[row * 4 + (c - 3)];
            else if (c < 10)  v = scl[row * 3 + (c - 7)];
            else if (c < 11)  { v = opa[row]; out[10 * NN + row] = v; }
            else if (c < 59)  v = shs[(size_t)row * 48 + (c - 11)];
            else if (c < 187) v = sem[(size_t)row * 128 + (c - 59)];
            else if (c < 190) v = dx[row * 3 + (c - 187)];
            else if (c < 191) v = te[row];
            else if (c < 255) { sv[j] = (short)enc[c - 191]; continue; }
            else v = 0.0f;
            sv[j] = (short)f2bf(fmaxf(v, 0.0f));
        }
    }
    *(short8*)(x + (size_t)row * 256 + c0) = sv;
}

// ---------------- fused 5-head MLP ----------------
struct FusedArgs {
    const u16* x; const u16* W1t; const u16* W2t;
    const float* b1[5]; const float* b2[5];
    const float* pt; const float* scl; const float* rot; const float* shs;
    float* out; int n; int rb;
};

// layer1 swapped: acc[ct][t] = D[m=h1col-tile ct][n=row-tile t]; lane(q,ln) reg r:
//   h1pre[c = ct*16 + q*4 + r][row = r0 + 16t + ln]
__device__ __forceinline__ void layer1_tile(const u16* __restrict__ x, const u16* W1L,
                                            int r0, int n, int q, int ln,
                                            floatx4 acc[16][2])
{
#pragma unroll
    for (int ct = 0; ct < 16; ++ct) {
        acc[ct][0] = (floatx4){0.f, 0.f, 0.f, 0.f};
        acc[ct][1] = (floatx4){0.f, 0.f, 0.f, 0.f};
    }
    const int ra = min(r0 + ln, n - 1);
    const int rbb = min(r0 + 16 + ln, n - 1);
    const u16* xr0 = x + (size_t)ra * 256 + q * 8;
    const u16* xr1 = x + (size_t)rbb * 256 + q * 8;
    short8 xf[2][8];
#pragma unroll
    for (int kk = 0; kk < 8; ++kk) {
        xf[0][kk] = *(const short8*)(xr0 + kk * 32);
        xf[1][kk] = *(const short8*)(xr1 + kk * 32);
    }
#pragma unroll
    for (int kk = 0; kk < 8; ++kk) {
#pragma unroll
        for (int ct = 0; ct < 16; ++ct) {
            int nidx = ct * 16 + ln;
            int sw = (kk * 4 + q) ^ (nidx & 31);
            short8 wf = *(const short8*)(W1L + nidx * 256 + (sw << 3));
            acc[ct][0] = __builtin_amdgcn_mfma_f32_16x16x32_bf16(wf, xf[0][kk], acc[ct][0], 0, 0, 0);
            acc[ct][1] = __builtin_amdgcn_mfma_f32_16x16x32_bf16(wf, xf[1][kk], acc[ct][1], 0, 0, 0);
        }
    }
}

// layer2: bias+relu in place; acc2[mt][t] = D2[m=n2][n=row] via MFMA(A2=W2t, B2=h1 via shfl)
template<int MT>
__device__ __forceinline__ void layer2_tile(floatx4 acc[16][2], const float* __restrict__ b1h,
                                            const u16* __restrict__ w2th, int q, int ln,
                                            floatx4 acc2[3][2])
{
#pragma unroll
    for (int ct = 0; ct < 16; ++ct) {
        floatx4 b4 = *(const floatx4*)(b1h + ct * 16 + q * 4);
#pragma unroll
        for (int t = 0; t < 2; ++t) {
            floatx4 v = acc[ct][t];
            v.x = fmaxf(v.x + b4.x, 0.f);
            v.y = fmaxf(v.y + b4.y, 0.f);
            v.z = fmaxf(v.z + b4.z, 0.f);
            v.w = fmaxf(v.w + b4.w, 0.f);
            if (ct == 15) v.w = (q == 3) ? 0.f : v.w;   // c==255 pad col (b1 OOB garbage)
            acc[ct][t] = v;
        }
    }
#pragma unroll
    for (int mt = 0; mt < MT; ++mt) {
        acc2[mt][0] = (floatx4){0.f, 0.f, 0.f, 0.f};
        acc2[mt][1] = (floatx4){0.f, 0.f, 0.f, 0.f};
    }
#pragma unroll
    for (int ks = 0; ks < 8; ++ks) {
        short8 a2[MT];
#pragma unroll
        for (int mt = 0; mt < MT; ++mt)
            a2[mt] = *(const short8*)(w2th + (mt * 16 + ln) * 256 + ks * 32 + q * 8);
#pragma unroll
        for (int t = 0; t < 2; ++t) {
            short8 bfrag;
#pragma unroll
            for (int j = 0; j < 8; ++j) {
                int idx = (((q * 2 + (j >> 2)) & 3) << 4) | ln;
                float v0 = __shfl(acc[ks * 2 + 0][t][j & 3], idx, 64);
                float v1 = __shfl(acc[ks * 2 + 1][t][j & 3], idx, 64);
                float v = (q >> 1) ? v1 : v0;
                bfrag[j] = (short)f2bf(v);
            }
#pragma unroll
            for (int mt = 0; mt < MT; ++mt)
                acc2[mt][t] = __builtin_amdgcn_mfma_f32_16x16x32_bf16(a2[mt], bfrag, acc2[mt][t], 0, 0, 0);
        }
    }
}

// epilogue: acc2 lane(q,ln) reg r: n2 = mt*16 + q*4 + r, row = r0 + 16t + ln
__device__ __forceinline__ void epi_head(int h, const FusedArgs& A, floatx4 acc2[3][2],
                                         float* maskL, int r0, int bstart, int rend,
                                         int q, int ln)
{
    const size_t NN = (size_t)A.n;
    const float* b2h = A.b2[h];
    if (h == 0) {
        if (q == 0) {
            float bb = b2h[0];
#pragma unroll
            for (int t = 0; t < 2; ++t) {
                int grow = r0 + 16 * t + ln;
                if (grow < rend) {
                    float m = 1.0f / (1.0f + expf(-(acc2[0][t][0] + bb)));
                    maskL[grow - bstart] = m;
                }
            }
        }
    } else if (h < 4) {
        const int od = (h == 3) ? 4 : 3;
        if (q == 0) {
#pragma unroll
            for (int t = 0; t < 2; ++t) {
                int grow = r0 + 16 * t + ln;
                if (grow < rend) {
                    float mk = maskL[grow - bstart];
                    if (h == 1) {
#pragma unroll
                        for (int r = 0; r < 3; ++r) {
                            float raw = acc2[0][t][r] + b2h[r];
                            A.out[59 * NN + (size_t)grow * 3 + r] = raw;
                            A.out[(size_t)grow * 3 + r] = A.pt[(size_t)grow * 3 + r] + raw * mk;
                        }
                    } else if (h == 2) {
#pragma unroll
                        for (int r = 0; r < 3; ++r) {
                            float raw = acc2[0][t][r] + b2h[r];
                            A.out[3 * NN + (size_t)grow * 3 + r] = A.scl[(size_t)grow * 3 + r] + raw * mk;
                        }
                    } else {
#pragma unroll
                        for (int r = 0; r < 4; ++r) {
                            float raw = acc2[0][t][r] + b2h[r];
                            A.out[6 * NN + (size_t)grow * 4 + r] = A.rot[(size_t)grow * 4 + r] + raw * mk;
                        }
                    }
                }
            }
        }
    } else {
#pragma unroll
        for (int t = 0; t < 2; ++t) {
            int grow = r0 + 16 * t + ln;
            if (grow < rend) {
                float mk = maskL[grow - bstart];
#pragma unroll
                for (int mt = 0; mt < 3; ++mt) {
                    int n2b = mt * 16 + q * 4;
                    floatx4 b2v = *(const floatx4*)(b2h + n2b);
                    floatx4 raw = acc2[mt][t] + b2v;
                    *(floatx4*)(A.out + 62 * NN + (size_t)grow * 48 + n2b) = raw;
                    floatx4 s = *(const floatx4*)(A.shs + (size_t)grow * 48 + n2b);
                    *(floatx4*)(A.out + 11 * NN + (size_t)grow * 48 + n2b) = s + raw * mk;
                }
            }
        }
    }
}

__global__ __launch_bounds__(512, 2) void fused_heads(FusedArgs A)
{
    extern __shared__ char smem[];
    u16* W1L = (u16*)smem;                       // 131072 B, swizzled W1 of current head
    float* maskL = (float*)(smem + 131072);      // 800 f32

    const int tid = threadIdx.x;
    const int wave = tid >> 6;
    const int lane = tid & 63;
    const int q = lane >> 4;
    const int ln = lane & 15;
    const int n = A.n;
    const int bstart = blockIdx.x * A.rb;
    const int rend = min(bstart + A.rb, n);

    stage_w1(A.W1t, W1L, wave, lane);            // head 0
    __syncthreads();

    floatx4 acc[16][2];
    floatx4 acc2[3][2];

    for (int h = 0; h < 5; ++h) {
        const float* b1h = A.b1[h];
        const int roff = (h < 4) ? h * 16 : 64;
        const u16* w2th = A.W2t + roff * 256;

        // rounds 0..2 fully fused
#pragma unroll 1
        for (int rnd = 0; rnd < 3; ++rnd) {
            int r0 = bstart + (wave + rnd * 8) * 32;
            if (r0 < rend) {
                layer1_tile(A.x, W1L, r0, n, q, ln, acc);
                if (h == 4) layer2_tile<3>(acc, b1h, w2th, q, ln, acc2);
                else        layer2_tile<1>(acc, b1h, w2th, q, ln, acc2);
                epi_head(h, A, acc2, maskL, r0, bstart, rend, q, ln);
            }
        }
        // round 3: layer1 before barrier, layer2 after prefetch (hides W1 DMA)
        int r0 = bstart + (wave + 24) * 32;
        bool v3 = (r0 < rend);
        if (v3) layer1_tile(A.x, W1L, r0, n, q, ln, acc);
        __syncthreads();
        if (h < 4) stage_w1(A.W1t + (h + 1) * 65536, W1L, wave, lane);
        if (v3) {
            if (h == 4) layer2_tile<3>(acc, b1h, w2th, q, ln, acc2);
            else        layer2_tile<1>(acc, b1h, w2th, q, ln, acc2);
            epi_head(h, A, acc2, maskL, r0, bstart, rend, q, ln);
        }
        __syncthreads();
    }
}

extern "C" void kernel_launch(void* const* d_in, const int* in_sizes, int n_in,
                              void* d_out, int out_size, void* d_ws, size_t ws_size,
                              hipStream_t stream)
{
    const float* opa  = (const float*)d_in[0];
    const float* shs  = (const float*)d_in[1];
    const float* te   = (const float*)d_in[2];
    const float* sem  = (const float*)d_in[3];
    const float* pt   = (const float*)d_in[4];
    const float* scl  = (const float*)d_in[5];
    const float* rot  = (const float*)d_in[6];
    const float* dx   = (const float*)d_in[7];

    WPtrs p;
    p.w1[0] = (const float*)d_in[8];  p.w2[0] = (const float*)d_in[10];
    p.w1[1] = (const float*)d_in[12]; p.w2[1] = (const float*)d_in[14];
    p.w1[2] = (const float*)d_in[16]; p.w2[2] = (const float*)d_in[18];
    p.w1[3] = (const float*)d_in[20]; p.w2[3] = (const float*)d_in[22];
    p.w1[4] = (const float*)d_in[24]; p.w2[4] = (const float*)d_in[26];

    const int n = in_sizes[0];               // 200000

    char* ws = (char*)d_ws;
    u16* x   = (u16*)ws;                                   // n*256 bf16
    u16* W1t = (u16*)(ws + (size_t)n * 256 * 2);           // 5*65536 bf16 (swizzled)
    u16* W2t = W1t + 5 * 65536;                            // 112*256 bf16
    u16* enc = W2t + 112 * 256;                            // 64 bf16

    prep_weights<<<193, 256, 0, stream>>>(p, te, W1t, W2t, enc);
    build_x<<<(n + 7) / 8, 256, 0, stream>>>(opa, shs, te, sem, pt, scl, rot, dx,
                                             enc, (float*)d_out, x, n);

    FusedArgs A;
    A.x = x; A.W1t = W1t; A.W2t = W2t;
    A.b1[0] = (const float*)d_in[9];  A.b2[0] = (const float*)d_in[11];
    A.b1[1] = (const float*)d_in[13]; A.b2[1] = (const float*)d_in[15];
    A.b1[2] = (const float*)d_in[17]; A.b2[2] = (const float*)d_in[19];
    A.b1[3] = (const float*)d_in[21]; A.b2[3] = (const float*)d_in[23];
    A.b1[4] = (const float*)d_in[25]; A.b2[4] = (const float*)d_in[27];
    A.pt = pt; A.scl = scl; A.rot = rot; A.shs = shs;
    A.out = (float*)d_out; A.n = n;
    A.rb = (n + 255) / 256;                  // 782 -> 25 tiles of 32 rows, 4 rounds x 8 waves

    int grid = (n + A.rb - 1) / A.rb;        // 256
    fused_heads<<<grid, 512, 131072 + 800 * 4, stream>>>(A);
}